// Round 1
// baseline (17469.917 us; speedup 1.0000x reference)
//
#include <hip/hip_runtime.h>

typedef unsigned short u16;
typedef short v8s __attribute__((ext_vector_type(8)));
typedef float v4f __attribute__((ext_vector_type(4)));

#define T_ 512
#define B_ 512
#define I_ 128
#define H_ 512
#define KK 640

__device__ inline u16 f2b(float x){
  union{float f; unsigned u;} v; v.f = x;
  unsigned r = v.u + 0x7fffu + ((v.u >> 16) & 1u);
  return (u16)(r >> 16);
}

// One-shot prep: bf16 weight repack (Wcat[gcol][k] = [W_ih | W_hh]), fc_W bf16,
// fused bias, h/c/out initial state. Runs every call (same work), ~negligible.
__global__ void init_kernel(const float* __restrict__ x, const float* __restrict__ h0,
    const float* __restrict__ c0, const float* __restrict__ Wih, const float* __restrict__ Whh,
    const float* __restrict__ bih, const float* __restrict__ bhh, const float* __restrict__ fcW,
    u16* __restrict__ Wcat, u16* __restrict__ fcWb, float* __restrict__ bsum,
    u16* __restrict__ hb0, float* __restrict__ cbuf, u16* __restrict__ outb)
{
  int idx = blockIdx.x * 256 + threadIdx.x;
  if (idx < 1310720) {                       // Wcat: 2048 x 640
    int g = idx / 640, k = idx - g * 640;
    float v = (k < 128) ? Wih[g * 128 + k] : Whh[g * 512 + (k - 128)];
    Wcat[idx] = f2b(v);
  } else if (idx < 1376256) {                // fcW bf16: 128 x 512
    int i = idx - 1310720; fcWb[i] = f2b(fcW[i]);
  } else if (idx < 1378304) {                // fused bias: 2048
    int i = idx - 1376256; bsum[i] = bih[i] + bhh[i];
  } else if (idx < 1640448) {                // h init: 512 x 512
    int i = idx - 1378304; hb0[i] = f2b(h0[i]);
  } else if (idx < 1902592) {                // c init: 512 x 512
    int i = idx - 1640448; cbuf[i] = c0[i];
  } else if (idx < 1968128) {                // inp init = x[511]: 512 x 128
    int i = idx - 1902592; outb[i] = f2b(x[33488896 + i]);
  }
}

// Gates + cell kernel. Grid 256 = 8 m-blocks (64 rows) x 32 n-blocks (16 H-cols).
// Wave g (0..3) computes gate g's [64 x 16] tile: gcols = g*512 + nw*16 + (lane&15).
// A = [out(128) | h(512)] staged to LDS in two 320-k halves; W streamed from L2.
__global__ __launch_bounds__(256) void gates_kernel(
    const u16* __restrict__ Wcat, const float* __restrict__ bsum,
    const u16* __restrict__ outb, const u16* __restrict__ hin,
    u16* __restrict__ hout, float* __restrict__ cbuf)
{
  __shared__ u16 Alds[64 * 328];     // 320 k + 8 pad -> stride 656B (bank-safe)
  __shared__ float gbuf[4 * 64 * 16];

  const int tid  = threadIdx.x;
  const int wave = tid >> 6, lane = tid & 63;
  const int n16  = lane & 15, q = lane >> 4;
  const int mb   = blockIdx.x >> 5, nw = blockIdx.x & 31;
  const int R    = mb * 64;
  const u16* wrow = Wcat + (wave * 512 + nw * 16 + n16) * KK;

  v4f acc[4];
  #pragma unroll
  for (int m = 0; m < 4; ++m) acc[m] = (v4f){0.f, 0.f, 0.f, 0.f};

  #pragma unroll
  for (int half = 0; half < 2; ++half) {
    const int kbase = half * 320;
    if (half) __syncthreads();               // prior half's A reads complete
    for (int j = 0; j < 10; ++j) {           // stage 64 rows x 40 chunks of 8 bf16
      int v = j * 256 + tid;
      int row = v / 40, cc = v - row * 40;
      int k = kbase + cc * 8;
      v8s val;
      if (k < 128) val = *reinterpret_cast<const v8s*>(outb + (R + row) * I_ + k);
      else         val = *reinterpret_cast<const v8s*>(hin  + (R + row) * H_ + (k - 128));
      *reinterpret_cast<v8s*>(&Alds[row * 328 + cc * 8]) = val;
    }
    __syncthreads();
    for (int kc = 0; kc < 10; ++kc) {
      int k0 = kc * 32 + q * 8;
      v8s b = *reinterpret_cast<const v8s*>(wrow + kbase + k0);   // B[k][n]=W[gcol][k]
      #pragma unroll
      for (int m = 0; m < 4; ++m) {
        v8s a = *reinterpret_cast<const v8s*>(&Alds[(m * 16 + n16) * 328 + k0]);
        acc[m] = __builtin_amdgcn_mfma_f32_16x16x32_bf16(a, b, acc[m], 0, 0, 0);
      }
    }
  }

  // Per-gate activation -> LDS exchange (i,f,o: sigmoid; g: tanh)
  float bias = bsum[wave * 512 + nw * 16 + n16];
  #pragma unroll
  for (int m = 0; m < 4; ++m) {
    #pragma unroll
    for (int r = 0; r < 4; ++r) {
      float z = acc[m][r] + bias;
      float a = (wave == 2) ? tanhf(z) : 1.f / (1.f + __expf(-z));
      gbuf[wave * 1024 + (m * 16 + q * 4 + r) * 16 + n16] = a;
    }
  }
  __syncthreads();

  // Cell update: c exclusive to this wg; h_new -> bf16 double buffer
  for (int j = 0; j < 4; ++j) {
    int e = j * 256 + tid;
    int row = e >> 4, col = e & 15;
    float ig = gbuf[0 * 1024 + row * 16 + col];
    float fg = gbuf[1 * 1024 + row * 16 + col];
    float gg = gbuf[2 * 1024 + row * 16 + col];
    float og = gbuf[3 * 1024 + row * 16 + col];
    int gi = (R + row) * H_ + nw * 16 + col;
    float cn = fg * cbuf[gi] + ig * gg;
    cbuf[gi] = cn;
    hout[gi] = f2b(og * tanhf(cn));
  }
}

// fc kernel: out = 2*sigmoid(h_new @ fc_W^T + fc_b) - 1. Grid 8 (64-row blocks),
// wave handles 32 I-cols. Writes f32 d_out slice (reversed index) + bf16 feedback.
__global__ __launch_bounds__(256) void fc_kernel(
    const u16* __restrict__ h, const u16* __restrict__ fcWb,
    const float* __restrict__ fcb, u16* __restrict__ outb,
    float* __restrict__ dout)
{
  const int tid  = threadIdx.x;
  const int wave = tid >> 6, lane = tid & 63;
  const int n16  = lane & 15, q = lane >> 4;
  const int R    = blockIdx.x * 64;

  v4f acc[4][2];
  #pragma unroll
  for (int m = 0; m < 4; ++m)
    for (int nt = 0; nt < 2; ++nt) acc[m][nt] = (v4f){0.f, 0.f, 0.f, 0.f};

  const u16* b0 = fcWb + (wave * 32 + n16) * H_;
  const u16* b1 = b0 + 16 * H_;
  for (int kc = 0; kc < 16; ++kc) {
    int k0 = kc * 32 + q * 8;
    v8s fb0 = *reinterpret_cast<const v8s*>(b0 + k0);
    v8s fb1 = *reinterpret_cast<const v8s*>(b1 + k0);
    #pragma unroll
    for (int m = 0; m < 4; ++m) {
      v8s a = *reinterpret_cast<const v8s*>(h + (R + m * 16 + n16) * H_ + k0);
      acc[m][0] = __builtin_amdgcn_mfma_f32_16x16x32_bf16(a, fb0, acc[m][0], 0, 0, 0);
      acc[m][1] = __builtin_amdgcn_mfma_f32_16x16x32_bf16(a, fb1, acc[m][1], 0, 0, 0);
    }
  }

  #pragma unroll
  for (int m = 0; m < 4; ++m) {
    #pragma unroll
    for (int nt = 0; nt < 2; ++nt) {
      int col = wave * 32 + nt * 16 + n16;
      float bb = fcb[col];
      #pragma unroll
      for (int r = 0; r < 4; ++r) {
        int row = R + m * 16 + q * 4 + r;
        float z = acc[m][nt][r] + bb;
        float o = 2.f / (1.f + __expf(-z)) - 1.f;
        dout[row * I_ + col] = o;        // f32 output (pre-offset to (511-t) slice)
        outb[row * I_ + col] = f2b(o);   // bf16 feedback for next step
      }
    }
  }
}

extern "C" void kernel_launch(void* const* d_in, const int* in_sizes, int n_in,
                              void* d_out, int out_size, void* d_ws, size_t ws_size,
                              hipStream_t stream)
{
  const float* x   = (const float*)d_in[0];
  // d_in[1] = enc_hiddens: unused by the reference
  const float* h0  = (const float*)d_in[2];
  const float* c0  = (const float*)d_in[3];
  const float* Wih = (const float*)d_in[4];
  const float* Whh = (const float*)d_in[5];
  const float* bih = (const float*)d_in[6];
  const float* bhh = (const float*)d_in[7];
  const float* fcW = (const float*)d_in[8];
  const float* fcb = (const float*)d_in[9];

  char* p = (char*)d_ws;
  u16*   Wcat = (u16*)p;   p += 2048LL * 640 * 2;
  u16*   fcWb = (u16*)p;   p += 128 * 512 * 2;
  float* bsum = (float*)p; p += 2048 * 4;
  u16*   hb0  = (u16*)p;   p += 512 * 512 * 2;
  u16*   hb1  = (u16*)p;   p += 512 * 512 * 2;
  float* cbuf = (float*)p; p += 512LL * 512 * 4;
  u16*   outb = (u16*)p;   p += 512 * 128 * 2;
  float* dout = (float*)d_out;

  init_kernel<<<7688, 256, 0, stream>>>(x, h0, c0, Wih, Whh, bih, bhh, fcW,
                                        Wcat, fcWb, bsum, hb0, cbuf, outb);
  for (int t = 0; t < 512; ++t) {
    const u16* hin  = (t & 1) ? hb1 : hb0;
    u16*       hout = (t & 1) ? hb0 : hb1;
    gates_kernel<<<256, 256, 0, stream>>>(Wcat, bsum, outb, hin, hout, cbuf);
    fc_kernel<<<8, 256, 0, stream>>>(hout, fcWb, fcb, outb,
                                     dout + (long long)(511 - t) * 65536);
  }
}